// Round 1
// baseline (121.406 us; speedup 1.0000x reference)
//
#include <hip/hip_runtime.h>
#include <math.h>

// NoisyTopkRouter: x[T,2048] @ {Wg,Wn}[8,2048]^T -> logits[T,8] each,
// noisy = noise * softplus(noisy_pre) + gate; top-2 -> softmax -> scatter.
// T = 32768, D = 2048, E = 8, k = 2.
// Memory-bound: 256 MB of x at ~6.3 TB/s -> ~41 us floor.

#define RD 2048
#define RE 8
#define RWAVES 4               // K-split across the block's 4 waves
#define TOKB 64                // tokens per block (one per lane)
#define KSEG (RD / RWAVES)     // 512 d's per wave

__global__ __launch_bounds__(256) void noisy_topk_router_kernel(
    const float* __restrict__ x,
    const float* __restrict__ Wg,
    const float* __restrict__ bg,
    const float* __restrict__ Wn,
    const float* __restrict__ bn,
    const float* __restrict__ noise,
    float* __restrict__ out_router,
    float* __restrict__ out_experts)
{
    __shared__ float part_g[RWAVES][TOKB][RE];   // 8 KB
    __shared__ float part_n[RWAVES][TOKB][RE];   // 8 KB

    const int w = threadIdx.x >> 6;          // wave id 0..3 -> K segment
    const int l = threadIdx.x & 63;          // lane -> token within tile
    const int t = blockIdx.x * TOKB + l;     // token id (grid sized exactly)
    // readfirstlane: make the K-segment base an SGPR so W addresses are
    // provably wave-uniform -> compiler emits s_load (scalar cache), keeping
    // weights entirely off the vector-memory path.
    const int d0 = __builtin_amdgcn_readfirstlane(w * KSEG);

    float accg[RE], accn[RE];
#pragma unroll
    for (int e = 0; e < RE; ++e) { accg[e] = 0.f; accn[e] = 0.f; }

    const float4* __restrict__ xrow =
        reinterpret_cast<const float4*>(x + (size_t)t * RD + d0);

#pragma unroll 2
    for (int j = 0; j < KSEG / 4; ++j) {
        const float4 xv = xrow[j];
        const int du = d0 + j * 4;
#pragma unroll
        for (int e = 0; e < RE; ++e) {
            const float4 wg = *reinterpret_cast<const float4*>(Wg + e * RD + du);
            accg[e] = fmaf(xv.x, wg.x, accg[e]);
            accg[e] = fmaf(xv.y, wg.y, accg[e]);
            accg[e] = fmaf(xv.z, wg.z, accg[e]);
            accg[e] = fmaf(xv.w, wg.w, accg[e]);
            const float4 wn = *reinterpret_cast<const float4*>(Wn + e * RD + du);
            accn[e] = fmaf(xv.x, wn.x, accn[e]);
            accn[e] = fmaf(xv.y, wn.y, accn[e]);
            accn[e] = fmaf(xv.z, wn.z, accn[e]);
            accn[e] = fmaf(xv.w, wn.w, accn[e]);
        }
    }

#pragma unroll
    for (int e = 0; e < RE; ++e) {
        part_g[w][l][e] = accg[e];
        part_n[w][l][e] = accn[e];
    }
    __syncthreads();

    if (threadIdx.x < TOKB) {
        // Combine the 4 K-segment partials (fixed order -> deterministic),
        // add biases.
        float g[RE], npre[RE];
#pragma unroll
        for (int e = 0; e < RE; ++e) {
            g[e]    = ((part_g[0][l][e] + part_g[1][l][e]) +
                       (part_g[2][l][e] + part_g[3][l][e])) + bg[e];
            npre[e] = ((part_n[0][l][e] + part_n[1][l][e]) +
                       (part_n[2][l][e] + part_n[3][l][e])) + bn[e];
        }

        const float4* nzp = reinterpret_cast<const float4*>(noise + (size_t)t * RE);
        const float4 nz0 = nzp[0];
        const float4 nz1 = nzp[1];
        const float nzv[RE] = {nz0.x, nz0.y, nz0.z, nz0.w,
                               nz1.x, nz1.y, nz1.z, nz1.w};

        float v[RE];
#pragma unroll
        for (int e = 0; e < RE; ++e) {
            const float p = npre[e];
            // stable softplus: max(p,0) + log1p(exp(-|p|))
            const float sp = fmaxf(p, 0.f) + log1pf(expf(-fabsf(p)));
            v[e] = fmaf(nzv[e], sp, g[e]);
        }

        // top-2 of 8; strict '>' keeps the lowest index on ties, matching
        // jax.lax.top_k / torch.topk ordering.
        int i1 = 0; float m1 = v[0];
#pragma unroll
        for (int e = 1; e < RE; ++e)
            if (v[e] > m1) { m1 = v[e]; i1 = e; }
        int i2 = -1; float m2 = -INFINITY;
#pragma unroll
        for (int e = 0; e < RE; ++e)
            if (e != i1 && v[e] > m2) { m2 = v[e]; i2 = e; }

        // softmax over the two kept logits
        const float e2 = expf(m2 - m1);
        const float inv = 1.f / (1.f + e2);
        const float p1 = inv;
        const float p2 = e2 * inv;

        float r[RE];
#pragma unroll
        for (int e = 0; e < RE; ++e)
            r[e] = (e == i1) ? p1 : ((e == i2) ? p2 : 0.f);

        float4* orow = reinterpret_cast<float4*>(out_router + (size_t)t * RE);
        orow[0] = make_float4(r[0], r[1], r[2], r[3]);
        orow[1] = make_float4(r[4], r[5], r[6], r[7]);

        // topexperts, written as float32 values into the concatenated out buf
        float2* erow = reinterpret_cast<float2*>(out_experts + (size_t)t * 2);
        *erow = make_float2((float)i1, (float)i2);
    }
}

extern "C" void kernel_launch(void* const* d_in, const int* in_sizes, int n_in,
                              void* d_out, int out_size, void* d_ws, size_t ws_size,
                              hipStream_t stream) {
    const float* x   = (const float*)d_in[0];
    const float* Wg  = (const float*)d_in[1];
    const float* bg  = (const float*)d_in[2];
    const float* Wn  = (const float*)d_in[3];
    const float* bn  = (const float*)d_in[4];
    const float* nz  = (const float*)d_in[5];
    const int T = in_sizes[0] / RD;              // 32768

    float* out_router  = (float*)d_out;          // T*8 floats
    float* out_experts = out_router + (size_t)T * RE;  // T*2 floats (as f32)

    const int blocks = T / TOKB;                 // 512
    hipLaunchKernelGGL(noisy_topk_router_kernel, dim3(blocks), dim3(256), 0,
                       stream, x, Wg, bg, Wn, bn, nz, out_router, out_experts);
}

// Round 2
// 107.261 us; speedup vs baseline: 1.1319x; 1.1319x over previous
//
#include <hip/hip_runtime.h>
#include <math.h>

// NoisyTopkRouter: x[T,2048] @ {Wg,Wn}[8,2048]^T -> logits[T,8] each,
// noisy = noise * softplus(noisy_pre) + gate; top-2 -> softmax -> scatter.
// T = 32768, D = 2048, E = 8, k = 2.
// R2: latency-bound fix — K-split 16 (1024-thread blocks) -> 32 waves/CU,
// 4-deep hoisted x loads for MLP. W stays on the scalar path (readfirstlane).

#define RD 2048
#define RE 8
#define RWAVES 16              // K-split across the block's 16 waves
#define TOKB 64                // tokens per block (one per lane)
#define KSEG (RD / RWAVES)     // 128 d's per wave

__global__ __launch_bounds__(1024) void noisy_topk_router_kernel(
    const float* __restrict__ x,
    const float* __restrict__ Wg,
    const float* __restrict__ bg,
    const float* __restrict__ Wn,
    const float* __restrict__ bn,
    const float* __restrict__ noise,
    float* __restrict__ out_router,
    float* __restrict__ out_experts)
{
    __shared__ float part_g[RWAVES][TOKB][RE];   // 32 KB
    __shared__ float part_n[RWAVES][TOKB][RE];   // 32 KB
    __shared__ float glog[TOKB][RE];             // 2 KB
    __shared__ float nlog[TOKB][RE];             // 2 KB

    const int w = threadIdx.x >> 6;          // wave id 0..15 -> K segment
    const int l = threadIdx.x & 63;          // lane -> token within tile
    const int t = blockIdx.x * TOKB + l;     // token id (grid sized exactly)
    // readfirstlane: make the K-segment base an SGPR so W addresses are
    // provably wave-uniform -> compiler emits s_load (scalar cache), keeping
    // weights entirely off the vector-memory path.
    const int d0 = __builtin_amdgcn_readfirstlane(w * KSEG);

    float accg[RE], accn[RE];
#pragma unroll
    for (int e = 0; e < RE; ++e) { accg[e] = 0.f; accn[e] = 0.f; }

    const float4* __restrict__ xrow =
        reinterpret_cast<const float4*>(x + (size_t)t * RD + d0);

    // KSEG/4 = 32 float4 steps; process 4 per body with hoisted loads so
    // 4 x-loads are in flight per wave at a time.
    for (int j = 0; j < KSEG / 4; j += 4) {
        const float4 xv0 = xrow[j + 0];
        const float4 xv1 = xrow[j + 1];
        const float4 xv2 = xrow[j + 2];
        const float4 xv3 = xrow[j + 3];
        const float4 xv[4] = {xv0, xv1, xv2, xv3};
#pragma unroll
        for (int u = 0; u < 4; ++u) {
            const int du = d0 + (j + u) * 4;
#pragma unroll
            for (int e = 0; e < RE; ++e) {
                const float4 wg = *reinterpret_cast<const float4*>(Wg + e * RD + du);
                accg[e] = fmaf(xv[u].x, wg.x, accg[e]);
                accg[e] = fmaf(xv[u].y, wg.y, accg[e]);
                accg[e] = fmaf(xv[u].z, wg.z, accg[e]);
                accg[e] = fmaf(xv[u].w, wg.w, accg[e]);
                const float4 wn = *reinterpret_cast<const float4*>(Wn + e * RD + du);
                accn[e] = fmaf(xv[u].x, wn.x, accn[e]);
                accn[e] = fmaf(xv[u].y, wn.y, accn[e]);
                accn[e] = fmaf(xv[u].z, wn.z, accn[e]);
                accn[e] = fmaf(xv[u].w, wn.w, accn[e]);
            }
        }
    }

#pragma unroll
    for (int e = 0; e < RE; ++e) {
        part_g[w][l][e] = accg[e];
        part_n[w][l][e] = accn[e];
    }
    __syncthreads();

    // Stage 1: 512 threads sum the 16 K-partials. tid -> (token, expert);
    // consecutive tids read consecutive LDS dwords -> conflict-free.
    if (threadIdx.x < TOKB * RE) {
        const int lt = threadIdx.x >> 3;     // token 0..63
        const int e  = threadIdx.x & 7;      // expert 0..7
        float sg = 0.f, sn = 0.f;
#pragma unroll
        for (int ww = 0; ww < RWAVES; ++ww) {
            sg += part_g[ww][lt][e];
            sn += part_n[ww][lt][e];
        }
        glog[lt][e] = sg + bg[e];
        nlog[lt][e] = sn + bn[e];
    }
    __syncthreads();

    // Stage 2: 64 threads, one token each — softplus/noise/top-2/softmax.
    if (threadIdx.x < TOKB) {
        const float4* nzp = reinterpret_cast<const float4*>(noise + (size_t)t * RE);
        const float4 nz0 = nzp[0];
        const float4 nz1 = nzp[1];
        const float nzv[RE] = {nz0.x, nz0.y, nz0.z, nz0.w,
                               nz1.x, nz1.y, nz1.z, nz1.w};

        float v[RE];
#pragma unroll
        for (int e = 0; e < RE; ++e) {
            const float p = nlog[l][e];
            // stable softplus: max(p,0) + log1p(exp(-|p|))
            const float sp = fmaxf(p, 0.f) + log1pf(expf(-fabsf(p)));
            v[e] = fmaf(nzv[e], sp, glog[l][e]);
        }

        // top-2 of 8; strict '>' keeps the lowest index on ties, matching
        // jax.lax.top_k / torch.topk ordering.
        int i1 = 0; float m1 = v[0];
#pragma unroll
        for (int e = 1; e < RE; ++e)
            if (v[e] > m1) { m1 = v[e]; i1 = e; }
        int i2 = -1; float m2 = -INFINITY;
#pragma unroll
        for (int e = 0; e < RE; ++e)
            if (e != i1 && v[e] > m2) { m2 = v[e]; i2 = e; }

        // softmax over the two kept logits
        const float e2 = expf(m2 - m1);
        const float inv = 1.f / (1.f + e2);
        const float p1 = inv;
        const float p2 = e2 * inv;

        float r[RE];
#pragma unroll
        for (int e = 0; e < RE; ++e)
            r[e] = (e == i1) ? p1 : ((e == i2) ? p2 : 0.f);

        float4* orow = reinterpret_cast<float4*>(out_router + (size_t)t * RE);
        orow[0] = make_float4(r[0], r[1], r[2], r[3]);
        orow[1] = make_float4(r[4], r[5], r[6], r[7]);

        // topexperts, written as float32 values into the concatenated out buf
        float2* erow = reinterpret_cast<float2*>(out_experts + (size_t)t * 2);
        *erow = make_float2((float)i1, (float)i2);
    }
}

extern "C" void kernel_launch(void* const* d_in, const int* in_sizes, int n_in,
                              void* d_out, int out_size, void* d_ws, size_t ws_size,
                              hipStream_t stream) {
    const float* x   = (const float*)d_in[0];
    const float* Wg  = (const float*)d_in[1];
    const float* bg  = (const float*)d_in[2];
    const float* Wn  = (const float*)d_in[3];
    const float* bn  = (const float*)d_in[4];
    const float* nz  = (const float*)d_in[5];
    const int T = in_sizes[0] / RD;              // 32768

    float* out_router  = (float*)d_out;          // T*8 floats
    float* out_experts = out_router + (size_t)T * RE;  // T*2 floats (as f32)

    const int blocks = T / TOKB;                 // 512
    hipLaunchKernelGGL(noisy_topk_router_kernel, dim3(blocks), dim3(1024), 0,
                       stream, x, Wg, bg, Wn, bn, nz, out_router, out_experts);
}